// Round 7
// baseline (9249.362 us; speedup 1.0000x reference)
//
#include <hip/hip_runtime.h>
#include <hip/hip_cooperative_groups.h>

namespace cg = cooperative_groups;

#define BB 16
#define TT 2048
#define HIDN 896
#define HALFN 448
#define NBINS 256
#define NWG 112
#define NTHR 64
#define WSTR 904            /* sW padded ushort stride */

typedef __attribute__((ext_vector_type(8))) short short8;
typedef __attribute__((ext_vector_type(4))) float f32x4;
typedef __attribute__((ext_vector_type(2))) unsigned long long ull2;

__device__ __forceinline__ unsigned short f2bf(float x) {
    unsigned int u = __float_as_uint(x);
    unsigned int r = u + 0x7FFFu + ((u >> 16) & 1u);
    return (unsigned short)(r >> 16);
}

// ---------------------------------------------------------------------------
// Persistent GRU scan. 112 WGs x 1 wave (64 thr). WG g owns h-cols [8g,8g+8).
// Lane (q=l&15, hi=l>>4). Tile A (sW rows 0..15) = {r cols 0..7, z cols 0..7};
// tile B (rows 16..23) = n cols 0..7 (24..31 zero). 2x28 MFMAs per step.
// h exchange: hx[2][112][2][16] u64 (4 bf16 cols each). Consumer lane loads
// producer wg'=4ks+hi's two u64s at batch q == its OWN A-fragment for K-step
// ks -- NO LDS staging at all. slots[112] padded to 64B lines; K-sliced
// wait/load pipelined with MFMAs. Single wave: no __syncthreads in loop.
// ---------------------------------------------------------------------------
__global__ __launch_bounds__(NTHR, 1)
void scan_kernel(const float* __restrict__ cond,
                 const int*   __restrict__ sig,
                 const int*   __restrict__ tcrs,
                 const float* __restrict__ Wc,
                 const float* __restrict__ Wf,
                 const float* __restrict__ Whh,
                 const float* __restrict__ b_ih,
                 const float* __restrict__ b_hh,
                 unsigned long long* __restrict__ hx,   // [2][112][32] u64
                 int* __restrict__ slots,               // [112*16] padded
                 unsigned short* __restrict__ hc_out,
                 float* __restrict__ lasth)
{
    __shared__ unsigned short sW[32 * WSTR];   // 57,856 B (only LDS)

    const int tid  = threadIdx.x;
    const int wg   = blockIdx.x;
    const int col0 = wg * 8;

    // ---- one-time: W slices -> LDS bf16 ----
    // rows 0..7: r-gate cols 0..7; rows 8..15: z-gate; rows 16..23: n-gate;
    // rows 24..31: zero.
    for (int idx = tid; idx < 32 * HIDN; idx += NTHR) {
        int j2 = idx & 31, k = idx >> 5;
        unsigned short wv = 0;
        if (j2 < 16)
            wv = f2bf(Whh[(size_t)k * 2688 + (j2 >> 3) * HIDN + col0 + (j2 & 7)]);
        else if (j2 < 24)
            wv = f2bf(Whh[(size_t)k * 2688 + 2 * HIDN + col0 + (j2 & 7)]);
        sW[j2 * WSTR + k] = wv;
    }
    if (tid == 0)
        __hip_atomic_store(&slots[wg * 16], 0, __ATOMIC_RELAXED, __HIP_MEMORY_SCOPE_AGENT);

    // ---- lane roles ----
    const int l  = tid;
    const int q  = l & 15;
    const int hi = l >> 4;
    const int gA   = q >> 3;            // 0 = r-gate, 1 = z-gate (tile A)
    const int colA = col0 + (q & 7);

    float wpA0, wpA1, wpA2, wpB0, wpB1, wpB2;
    if (colA < HALFN) {
        wpA0 = Wc[gA * HALFN + colA];
        wpA1 = Wc[1344 + gA * HALFN + colA];
        wpA2 = 0.f;
        wpB0 = Wc[2 * HALFN + colA];
        wpB1 = Wc[1344 + 2 * HALFN + colA];
        wpB2 = 0.f;
    } else {
        int ck = colA - HALFN;
        wpA0 = Wf[gA * HALFN + ck];
        wpA1 = Wf[1344 + gA * HALFN + ck];
        wpA2 = Wf[2688 + gA * HALFN + ck];
        wpB0 = Wf[2 * HALFN + ck];
        wpB1 = Wf[1344 + 2 * HALFN + ck];
        wpB2 = Wf[2688 + 2 * HALFN + ck];
    }
    const float biA = b_ih[gA * HIDN + colA];
    const float bhA = b_hh[gA * HIDN + colA];
    const float biB = b_ih[2 * HIDN + colA];
    const float bhB = b_hh[2 * HIDN + colA];

    float hp[4] = {0.f, 0.f, 0.f, 0.f};

    __syncthreads();                 // sW visible wave-wide
    cg::this_grid().sync();          // slot clears visible grid-wide

    const float inv = 1.f / 127.5f;
    const int zsrc = (l & 48) | 8 | (q & 7);   // z-lane, same hi

#define WAITS(s) { bool ok_;                                                   \
    for (;;) {                                                                 \
        ok_ = true;                                                            \
        if (l < 28) {                                                          \
            int a_ = __hip_atomic_load(&slots[((s)*28 + l) * 16],              \
                __ATOMIC_RELAXED, __HIP_MEMORY_SCOPE_AGENT);                   \
            ok_ = (a_ >= t);                                                   \
        }                                                                      \
        if (__all(ok_)) break;                                                 \
        __builtin_amdgcn_s_sleep(1);                                           \
    }                                                                          \
    asm volatile("" ::: "memory"); }

    // Lane (q,hi): A-frag for K-step ks = cols 32ks+8hi..+7 of batch q
    //            = producer wg'=4ks+hi, halves 0/1, batch q.
#define LOADF(s, V) _Pragma("unroll")                                          \
    for (int i_ = 0; i_ < 7; ++i_) {                                           \
        _Pragma("unroll")                                                      \
        for (int h_ = 0; h_ < 2; ++h_)                                         \
            V[2*i_ + h_] = __hip_atomic_load(                                  \
                &hb[(size_t)(4 * ((s)*7 + i_) + hi) * 32 + h_ * 16 + q],       \
                __ATOMIC_RELAXED, __HIP_MEMORY_SCOPE_AGENT);                   \
    }

#define MFMAS(s, V) _Pragma("unroll")                                          \
    for (int i_ = 0; i_ < 7; ++i_) {                                           \
        ull2 tv_; tv_.x = V[2*i_]; tv_.y = V[2*i_ + 1];                        \
        short8 av_ = __builtin_bit_cast(short8, tv_);                          \
        int ks_ = (s)*7 + i_;                                                  \
        short8 b1_ = *(const short8*)&sW[q * WSTR + hi * 8 + ks_ * 32];        \
        chA[ks_ & 3] = __builtin_amdgcn_mfma_f32_16x16x32_bf16(                \
            av_, b1_, chA[ks_ & 3], 0, 0, 0);                                  \
        short8 b2_ = *(const short8*)&sW[(16 + q) * WSTR + hi * 8 + ks_ * 32]; \
        chB[ks_ & 3] = __builtin_amdgcn_mfma_f32_16x16x32_bf16(                \
            av_, b2_, chB[ks_ & 3], 0, 0, 0);                                  \
    }

    for (int t = 0; t < TT; ++t) {
        // ---- x_t loads (issued early; latency hides under h-wait) ----
        float xcA[4], xcB[4], sg0[4], sg1[4], sg2[4];
        #pragma unroll
        for (int r = 0; r < 4; ++r) {
            int b = hi * 4 + r;
            size_t bt = (size_t)b * TT + t;
            xcA[r] = cond[(bt * 3 + gA) * HIDN + colA];
            xcB[r] = cond[(bt * 3 + 2) * HIDN + colA];
            sg0[r] = (float)sig[bt * 2 + 0] * inv - 1.f;
            sg1[r] = (float)sig[bt * 2 + 1] * inv - 1.f;
            sg2[r] = (float)tcrs[bt] * inv - 1.f;
        }

        f32x4 chA[4] = {}, chB[4] = {};
        if (t > 0) {
            const unsigned long long* hb = hx + (size_t)(t & 1) * 3584;
            unsigned long long va[14], vb[14];
            WAITS(0); LOADF(0, va);
            WAITS(1); LOADF(1, vb);
            MFMAS(0, va);
            WAITS(2); LOADF(2, va);
            MFMAS(1, vb);
            WAITS(3); LOADF(3, vb);
            MFMAS(2, va);
            MFMAS(3, vb);
        }
        f32x4 aA = (chA[0] + chA[1]) + (chA[2] + chA[3]);
        f32x4 aB = (chB[0] + chB[1]) + (chB[2] + chB[3]);

        // ---- gates ----
        float xvA[4], xvB[4], sigA[4];
        #pragma unroll
        for (int r = 0; r < 4; ++r) {
            xvA[r] = xcA[r] + biA + sg0[r]*wpA0 + sg1[r]*wpA1 + sg2[r]*wpA2;
            xvB[r] = xcB[r] + biB + sg0[r]*wpB0 + sg1[r]*wpB1 + sg2[r]*wpB2;
            sigA[r] = 1.f / (1.f + __expf(-(xvA[r] + aA[r] + bhA)));
        }
        float hnv[4];
        unsigned short hbits[4] = {0, 0, 0, 0};
        #pragma unroll
        for (int r = 0; r < 4; ++r) {
            float zz = __shfl(sigA[r], zsrc);          // z from q+8 lane
            float a2v = xvB[r] + sigA[r] * (aB[r] + bhB);  // r on q<8 lanes
            float e = __expf(-2.f * a2v);
            float n = (1.f - e) / (1.f + e);
            float hn = (1.f - zz) * n + zz * hp[r];
            hnv[r] = hn;
            if (q < 8) { hp[r] = hn; hbits[r] = f2bf(hn); }
        }
        if (t == TT - 1 && q < 8) {
            #pragma unroll
            for (int r = 0; r < 4; ++r)
                lasth[(size_t)(hi * 4 + r) * HIDN + colA] = hnv[r];
        }

        // ---- pack 8 cols -> 2 u64 per batch; store; drain; publish ----
        unsigned p32[4];
        unsigned long long hv64[4];
        #pragma unroll
        for (int r = 0; r < 4; ++r) {
            int o1 = __shfl_xor((int)(unsigned)hbits[r], 1);
            p32[r] = ((unsigned)hbits[r] & 0xffffu) | ((unsigned)o1 << 16);
            int o2 = __shfl_xor((int)p32[r], 2);
            hv64[r] = (unsigned long long)p32[r] |
                      ((unsigned long long)(unsigned)o2 << 32);
        }
        if (t < TT - 1 && (q == 0 || q == 4)) {
            unsigned long long* hd = hx + (size_t)((t + 1) & 1) * 3584;
            #pragma unroll
            for (int r = 0; r < 4; ++r)
                __hip_atomic_store(&hd[(size_t)wg * 32 + (q >> 2) * 16 + hi * 4 + r],
                                   hv64[r], __ATOMIC_RELAXED, __HIP_MEMORY_SCOPE_AGENT);
        }
        asm volatile("s_waitcnt vmcnt(0)" ::: "memory");
        if (tid == 0)
            __hip_atomic_store(&slots[wg * 16], t + 1,
                               __ATOMIC_RELAXED, __HIP_MEMORY_SCOPE_AGENT);

        // ---- post-publish: history write (off critical path) ----
        if (wg < 56 && q < 8 && !(q & 1)) {
            unsigned* hc32 = (unsigned*)hc_out;
            #pragma unroll
            for (int r = 0; r < 4; ++r)
                hc32[((size_t)(hi * 4 + r) * TT + t) * 224 + wg * 4 + (q >> 1)] = p32[r];
        }
    }
#undef WAITS
#undef LOADF
#undef MFMAS
}

// ---------------------------------------------------------------------------
// Head GEMM: C(M x N) = [relu](A_bf16(M x 448) @ Bw(448 x N) + bias)
// ---------------------------------------------------------------------------
template<int RELU_BF16>
__global__ __launch_bounds__(256)
void head_gemm(const unsigned short* __restrict__ A,
               const float* __restrict__ Bw,
               const float* __restrict__ bias,
               unsigned short* __restrict__ Cb,
               float* __restrict__ Cf,
               int N)
{
    const int K = 448;
    __shared__ float As[32][68];
    __shared__ float Bs[32][68];
    const int tid = threadIdx.x;
    const int tx = tid & 15;
    const int ty = tid >> 4;
    const int bm = blockIdx.x * 64;
    const int bn = blockIdx.y * 64;

    float acc[4][4] = {};

    for (int k0 = 0; k0 < K; k0 += 32) {
        #pragma unroll
        for (int it = 0; it < 2; ++it) {
            int idx = tid + it * 256;
            int m   = idx >> 3;
            int k4  = idx & 7;
            ushort4 av = *(const ushort4*)(A + (size_t)(bm + m) * K + k0 + k4 * 4);
            As[k4 * 4 + 0][m] = __uint_as_float((unsigned)av.x << 16);
            As[k4 * 4 + 1][m] = __uint_as_float((unsigned)av.y << 16);
            As[k4 * 4 + 2][m] = __uint_as_float((unsigned)av.z << 16);
            As[k4 * 4 + 3][m] = __uint_as_float((unsigned)av.w << 16);
        }
        #pragma unroll
        for (int it = 0; it < 2; ++it) {
            int idx = tid + it * 256;
            int k   = idx >> 4;
            int n4  = idx & 15;
            *(float4*)&Bs[k][n4 * 4] =
                *(const float4*)(Bw + (size_t)(k0 + k) * N + bn + n4 * 4);
        }
        __syncthreads();
        #pragma unroll
        for (int k = 0; k < 32; ++k) {
            float4 a4 = *(float4*)&As[k][ty * 4];
            float4 b4 = *(float4*)&Bs[k][tx * 4];
            float ar[4] = {a4.x, a4.y, a4.z, a4.w};
            float br[4] = {b4.x, b4.y, b4.z, b4.w};
            #pragma unroll
            for (int i = 0; i < 4; ++i)
                #pragma unroll
                for (int j = 0; j < 4; ++j)
                    acc[i][j] = fmaf(ar[i], br[j], acc[i][j]);
        }
        __syncthreads();
    }

    float4 bsv = *(const float4*)(bias + bn + tx * 4);
    float bb[4] = {bsv.x, bsv.y, bsv.z, bsv.w};
    #pragma unroll
    for (int i = 0; i < 4; ++i) {
        int row = bm + ty * 4 + i;
        float v[4];
        #pragma unroll
        for (int j = 0; j < 4; ++j) v[j] = acc[i][j] + bb[j];
        if (RELU_BF16) {
            ushort4 o;
            o.x = f2bf(fmaxf(v[0], 0.f));
            o.y = f2bf(fmaxf(v[1], 0.f));
            o.z = f2bf(fmaxf(v[2], 0.f));
            o.w = f2bf(fmaxf(v[3], 0.f));
            *(ushort4*)(Cb + (size_t)row * N + bn + tx * 4) = o;
        } else {
            float4 o = make_float4(v[0], v[1], v[2], v[3]);
            *(float4*)(Cf + (size_t)row * N + bn + tx * 4) = o;
        }
    }
}

// ---------------------------------------------------------------------------
extern "C" void kernel_launch(void* const* d_in, const int* in_sizes, int n_in,
                              void* d_out, int out_size, void* d_ws, size_t ws_size,
                              hipStream_t stream)
{
    const float* cond = (const float*)d_in[0];
    const int*   sig  = (const int*)d_in[1];
    const int*   tcrs = (const int*)d_in[2];
    const float* Wc   = (const float*)d_in[3];
    const float* Wf   = (const float*)d_in[4];
    const float* Whh  = (const float*)d_in[5];
    const float* bih  = (const float*)d_in[6];
    const float* bhh  = (const float*)d_in[7];
    const float* W1c  = (const float*)d_in[8];
    const float* b1c  = (const float*)d_in[9];
    const float* W2c  = (const float*)d_in[10];
    const float* b2c  = (const float*)d_in[11];
    const float* W1f  = (const float*)d_in[12];
    const float* b1f  = (const float*)d_in[13];
    const float* W2f  = (const float*)d_in[14];
    const float* b2f  = (const float*)d_in[15];

    char* ws = (char*)d_ws;
    int* slots               = (int*)ws;                         // 7,168 B (8K pad)
    unsigned long long* hx   = (unsigned long long*)(ws + 8192); // 57,344 B
    unsigned short* hc       = (unsigned short*)(ws + 65536);    // 29,360,128 B
    unsigned short* hid1     = (unsigned short*)(ws + 65536 + 29360128);

    float* outc  = (float*)d_out;
    float* outf  = outc + (size_t)BB * TT * NBINS;
    float* lasth = outc + 2 * (size_t)BB * TT * NBINS;

    void* args[] = {(void*)&cond, (void*)&sig, (void*)&tcrs, (void*)&Wc, (void*)&Wf,
                    (void*)&Whh, (void*)&bih, (void*)&bhh,
                    (void*)&hx, (void*)&slots, (void*)&hc, (void*)&lasth};
    hipLaunchCooperativeKernel((void*)scan_kernel, dim3(NWG), dim3(NTHR),
                               args, 0, stream);

    dim3 blk(256);
    head_gemm<1><<<dim3(512, 7), blk, 0, stream>>>(hc,   W1c, b1c, hid1, nullptr, 448);
    head_gemm<0><<<dim3(512, 4), blk, 0, stream>>>(hid1, W2c, b2c, nullptr, outc, 256);
    head_gemm<1><<<dim3(512, 7), blk, 0, stream>>>(hc,   W1f, b1f, hid1, nullptr, 448);
    head_gemm<0><<<dim3(512, 4), blk, 0, stream>>>(hid1, W2f, b2f, nullptr, outf, 256);
}

// Round 9
// 8177.666 us; speedup vs baseline: 1.1311x; 1.1311x over previous
//
#include <hip/hip_runtime.h>
#include <hip/hip_cooperative_groups.h>

namespace cg = cooperative_groups;

#define BB 16
#define TT 2048
#define HIDN 896
#define HALFN 448
#define NBINS 256
#define NWG 112
#define NTHR 64
#define WSTR 904            /* sW padded ushort stride */

typedef __attribute__((ext_vector_type(8))) short short8;
typedef __attribute__((ext_vector_type(4))) float f32x4;
typedef __attribute__((ext_vector_type(2))) unsigned long long ull2;

__device__ __forceinline__ unsigned short f2bf(float x) {
    unsigned int u = __float_as_uint(x);
    unsigned int r = u + 0x7FFFu + ((u >> 16) & 1u);
    return (unsigned short)(r >> 16);
}

// ---------------------------------------------------------------------------
// Persistent GRU scan. 112 WGs x 1 wave (64 thr). WG wg owns col-block
// cb = (wg&7)*14 + (wg>>3)  (XCD remap: same-XCD WGs own adjacent blocks,
// sharing cond cache lines), i.e. h-cols [8cb, 8cb+8).
// Lane (q=l&15, hi=l>>4). Tile A (sW rows 0..15) = {r cols, z cols};
// tile B (rows 16..23) = n cols (24..31 zero). 2x28 MFMAs per step.
// h exchange: hx[2][112][2][16] u64 indexed by cb; consumer lane loads
// producer cb'=4ks+hi's two u64s at batch q == its OWN A-fragment (no LDS
// staging). ONE wait on all 112 slots per step, then all 56 h-loads stream
// interleaved with MFMAs. Single wave: no __syncthreads in the loop.
// LDS kept at exactly 57,856 B (empirical coop-launch envelope for 64-thr).
// ---------------------------------------------------------------------------
__global__ __launch_bounds__(NTHR, 1)
void scan_kernel(const float* __restrict__ cond,
                 const int*   __restrict__ sig,
                 const int*   __restrict__ tcrs,
                 const float* __restrict__ Wc,
                 const float* __restrict__ Wf,
                 const float* __restrict__ Whh,
                 const float* __restrict__ b_ih,
                 const float* __restrict__ b_hh,
                 unsigned long long* __restrict__ hx,   // [2][112][32] u64 (by cb)
                 int* __restrict__ slots,               // [112*16] padded
                 unsigned short* __restrict__ hc_out,
                 float* __restrict__ lasth)
{
    __shared__ unsigned short sW[32 * WSTR];   // 57,856 B (only LDS)

    const int tid  = threadIdx.x;
    const int wg   = blockIdx.x;
    const int cb   = (wg & 7) * 14 + (wg >> 3);   // XCD-contiguous col-block
    const int col0 = cb * 8;

    // ---- one-time: W slices -> LDS bf16 ----
    for (int idx = tid; idx < 32 * HIDN; idx += NTHR) {
        int j2 = idx & 31, k = idx >> 5;
        unsigned short wv = 0;
        if (j2 < 16)
            wv = f2bf(Whh[(size_t)k * 2688 + (j2 >> 3) * HIDN + col0 + (j2 & 7)]);
        else if (j2 < 24)
            wv = f2bf(Whh[(size_t)k * 2688 + 2 * HIDN + col0 + (j2 & 7)]);
        sW[j2 * WSTR + k] = wv;
    }
    if (tid == 0)
        __hip_atomic_store(&slots[wg * 16], 0, __ATOMIC_RELAXED, __HIP_MEMORY_SCOPE_AGENT);

    // ---- lane roles ----
    const int l  = tid;
    const int q  = l & 15;
    const int hi = l >> 4;
    const int gA   = q >> 3;            // 0 = r-gate, 1 = z-gate (tile A)
    const int colA = col0 + (q & 7);

    float wpA0, wpA1, wpA2, wpB0, wpB1, wpB2;
    if (colA < HALFN) {
        wpA0 = Wc[gA * HALFN + colA];
        wpA1 = Wc[1344 + gA * HALFN + colA];
        wpA2 = 0.f;
        wpB0 = Wc[2 * HALFN + colA];
        wpB1 = Wc[1344 + 2 * HALFN + colA];
        wpB2 = 0.f;
    } else {
        int ck = colA - HALFN;
        wpA0 = Wf[gA * HALFN + ck];
        wpA1 = Wf[1344 + gA * HALFN + ck];
        wpA2 = Wf[2688 + gA * HALFN + ck];
        wpB0 = Wf[2 * HALFN + ck];
        wpB1 = Wf[1344 + 2 * HALFN + ck];
        wpB2 = Wf[2688 + 2 * HALFN + ck];
    }
    const float biA = b_ih[gA * HIDN + colA];
    const float bhA = b_hh[gA * HIDN + colA];
    const float biB = b_ih[2 * HIDN + colA];
    const float bhB = b_hh[2 * HIDN + colA];

    float hp[4] = {0.f, 0.f, 0.f, 0.f};

    __syncthreads();                 // sW visible wave-wide
    cg::this_grid().sync();          // slot clears visible grid-wide

    const float inv = 1.f / 127.5f;
    const int zsrc = (l & 48) | 8 | (q & 7);   // z-lane, same hi

    // ---- single wait on all 112 producer slots ----
#define WAITALL(t) { bool ok_;                                                 \
    for (;;) {                                                                 \
        int a_ = __hip_atomic_load(&slots[l * 16],                             \
            __ATOMIC_RELAXED, __HIP_MEMORY_SCOPE_AGENT);                       \
        int b_ = (l < 48) ? __hip_atomic_load(&slots[(l + 64) * 16],           \
            __ATOMIC_RELAXED, __HIP_MEMORY_SCOPE_AGENT) : a_;                  \
        ok_ = (a_ >= (t)) & (b_ >= (t));                                       \
        if (__all(ok_)) break;                                                 \
        __builtin_amdgcn_s_sleep(1);                                           \
    }                                                                          \
    asm volatile("" ::: "memory"); }

    // Lane (q,hi): A-frag for K-step ks = cols of col-block 4ks+hi, batch q.
#define LOADH(s, V) _Pragma("unroll")                                          \
    for (int i_ = 0; i_ < 7; ++i_) {                                           \
        _Pragma("unroll")                                                      \
        for (int h_ = 0; h_ < 2; ++h_)                                         \
            V[2*i_ + h_] = __hip_atomic_load(                                  \
                &hb[(size_t)(4 * ((s)*7 + i_) + hi) * 32 + h_ * 16 + q],       \
                __ATOMIC_RELAXED, __HIP_MEMORY_SCOPE_AGENT);                   \
    }

#define MFMAS(s, V) _Pragma("unroll")                                          \
    for (int i_ = 0; i_ < 7; ++i_) {                                           \
        ull2 tv_; tv_.x = V[2*i_]; tv_.y = V[2*i_ + 1];                        \
        short8 av_ = __builtin_bit_cast(short8, tv_);                          \
        int ks_ = (s)*7 + i_;                                                  \
        short8 b1_ = *(const short8*)&sW[q * WSTR + hi * 8 + ks_ * 32];        \
        chA[ks_ & 3] = __builtin_amdgcn_mfma_f32_16x16x32_bf16(                \
            av_, b1_, chA[ks_ & 3], 0, 0, 0);                                  \
        short8 b2_ = *(const short8*)&sW[(16 + q) * WSTR + hi * 8 + ks_ * 32]; \
        chB[ks_ & 3] = __builtin_amdgcn_mfma_f32_16x16x32_bf16(                \
            av_, b2_, chB[ks_ & 3], 0, 0, 0);                                  \
    }

    for (int t = 0; t < TT; ++t) {
        // ---- x_t loads (issued early; latency hides under h-wait) ----
        float xcA[4], xcB[4], sg0[4], sg1[4], sg2[4];
        #pragma unroll
        for (int r = 0; r < 4; ++r) {
            int b = hi * 4 + r;
            size_t bt = (size_t)b * TT + t;
            xcA[r] = cond[(bt * 3 + gA) * HIDN + colA];
            xcB[r] = cond[(bt * 3 + 2) * HIDN + colA];
            sg0[r] = (float)sig[bt * 2 + 0] * inv - 1.f;
            sg1[r] = (float)sig[bt * 2 + 1] * inv - 1.f;
            sg2[r] = (float)tcrs[bt] * inv - 1.f;
        }

        f32x4 chA[4] = {}, chB[4] = {};
        if (t > 0) {
            WAITALL(t);
            const unsigned long long* hb = hx + (size_t)(t & 1) * 3584;
            unsigned long long va[14], vb[14];
            LOADH(0, va);
            LOADH(1, vb);
            MFMAS(0, va);
            LOADH(2, va);
            MFMAS(1, vb);
            LOADH(3, vb);
            MFMAS(2, va);
            MFMAS(3, vb);
        }
        f32x4 aA = (chA[0] + chA[1]) + (chA[2] + chA[3]);
        f32x4 aB = (chB[0] + chB[1]) + (chB[2] + chB[3]);

        // ---- gates ----
        float xvA[4], xvB[4], sigA[4];
        #pragma unroll
        for (int r = 0; r < 4; ++r) {
            xvA[r] = xcA[r] + biA + sg0[r]*wpA0 + sg1[r]*wpA1 + sg2[r]*wpA2;
            xvB[r] = xcB[r] + biB + sg0[r]*wpB0 + sg1[r]*wpB1 + sg2[r]*wpB2;
            sigA[r] = 1.f / (1.f + __expf(-(xvA[r] + aA[r] + bhA)));
        }
        float hnv[4];
        unsigned short hbits[4] = {0, 0, 0, 0};
        #pragma unroll
        for (int r = 0; r < 4; ++r) {
            float zz = __shfl(sigA[r], zsrc);          // z from q+8 lane
            float a2v = xvB[r] + sigA[r] * (aB[r] + bhB);  // r on q<8 lanes
            float e = __expf(-2.f * a2v);
            float n = (1.f - e) / (1.f + e);
            float hn = (1.f - zz) * n + zz * hp[r];
            hnv[r] = hn;
            if (q < 8) { hp[r] = hn; hbits[r] = f2bf(hn); }
        }
        if (t == TT - 1 && q < 8) {
            #pragma unroll
            for (int r = 0; r < 4; ++r)
                lasth[(size_t)(hi * 4 + r) * HIDN + colA] = hnv[r];
        }

        // ---- pack 8 cols -> 2 u64 per batch; store; drain; publish ----
        unsigned p32[4];
        unsigned long long hv64[4];
        #pragma unroll
        for (int r = 0; r < 4; ++r) {
            int o1 = __shfl_xor((int)(unsigned)hbits[r], 1);
            p32[r] = ((unsigned)hbits[r] & 0xffffu) | ((unsigned)o1 << 16);
            int o2 = __shfl_xor((int)p32[r], 2);
            hv64[r] = (unsigned long long)p32[r] |
                      ((unsigned long long)(unsigned)o2 << 32);
        }
        if (t < TT - 1 && (q == 0 || q == 4)) {
            unsigned long long* hd = hx + (size_t)((t + 1) & 1) * 3584;
            #pragma unroll
            for (int r = 0; r < 4; ++r)
                __hip_atomic_store(&hd[(size_t)cb * 32 + (q >> 2) * 16 + hi * 4 + r],
                                   hv64[r], __ATOMIC_RELAXED, __HIP_MEMORY_SCOPE_AGENT);
        }
        asm volatile("s_waitcnt vmcnt(0)" ::: "memory");
        if (tid == 0)
            __hip_atomic_store(&slots[wg * 16], t + 1,
                               __ATOMIC_RELAXED, __HIP_MEMORY_SCOPE_AGENT);

        // ---- post-publish: history write (off critical path) ----
        if (cb < 56 && q < 8 && !(q & 1)) {
            unsigned* hc32 = (unsigned*)hc_out;
            #pragma unroll
            for (int r = 0; r < 4; ++r)
                hc32[((size_t)(hi * 4 + r) * TT + t) * 224 + cb * 4 + (q >> 1)] = p32[r];
        }
    }
#undef WAITALL
#undef LOADH
#undef MFMAS
}

// ---------------------------------------------------------------------------
// Head GEMM: C(M x N) = [relu](A_bf16(M x 448) @ Bw(448 x N) + bias)
// ---------------------------------------------------------------------------
template<int RELU_BF16>
__global__ __launch_bounds__(256)
void head_gemm(const unsigned short* __restrict__ A,
               const float* __restrict__ Bw,
               const float* __restrict__ bias,
               unsigned short* __restrict__ Cb,
               float* __restrict__ Cf,
               int N)
{
    const int K = 448;
    __shared__ float As[32][68];
    __shared__ float Bs[32][68];
    const int tid = threadIdx.x;
    const int tx = tid & 15;
    const int ty = tid >> 4;
    const int bm = blockIdx.x * 64;
    const int bn = blockIdx.y * 64;

    float acc[4][4] = {};

    for (int k0 = 0; k0 < K; k0 += 32) {
        #pragma unroll
        for (int it = 0; it < 2; ++it) {
            int idx = tid + it * 256;
            int m   = idx >> 3;
            int k4  = idx & 7;
            ushort4 av = *(const ushort4*)(A + (size_t)(bm + m) * K + k0 + k4 * 4);
            As[k4 * 4 + 0][m] = __uint_as_float((unsigned)av.x << 16);
            As[k4 * 4 + 1][m] = __uint_as_float((unsigned)av.y << 16);
            As[k4 * 4 + 2][m] = __uint_as_float((unsigned)av.z << 16);
            As[k4 * 4 + 3][m] = __uint_as_float((unsigned)av.w << 16);
        }
        #pragma unroll
        for (int it = 0; it < 2; ++it) {
            int idx = tid + it * 256;
            int k   = idx >> 4;
            int n4  = idx & 15;
            *(float4*)&Bs[k][n4 * 4] =
                *(const float4*)(Bw + (size_t)(k0 + k) * N + bn + n4 * 4);
        }
        __syncthreads();
        #pragma unroll
        for (int k = 0; k < 32; ++k) {
            float4 a4 = *(float4*)&As[k][ty * 4];
            float4 b4 = *(float4*)&Bs[k][tx * 4];
            float ar[4] = {a4.x, a4.y, a4.z, a4.w};
            float br[4] = {b4.x, b4.y, b4.z, b4.w};
            #pragma unroll
            for (int i = 0; i < 4; ++i)
                #pragma unroll
                for (int j = 0; j < 4; ++j)
                    acc[i][j] = fmaf(ar[i], br[j], acc[i][j]);
        }
        __syncthreads();
    }

    float4 bsv = *(const float4*)(bias + bn + tx * 4);
    float bb[4] = {bsv.x, bsv.y, bsv.z, bsv.w};
    #pragma unroll
    for (int i = 0; i < 4; ++i) {
        int row = bm + ty * 4 + i;
        float v[4];
        #pragma unroll
        for (int j = 0; j < 4; ++j) v[j] = acc[i][j] + bb[j];
        if (RELU_BF16) {
            ushort4 o;
            o.x = f2bf(fmaxf(v[0], 0.f));
            o.y = f2bf(fmaxf(v[1], 0.f));
            o.z = f2bf(fmaxf(v[2], 0.f));
            o.w = f2bf(fmaxf(v[3], 0.f));
            *(ushort4*)(Cb + (size_t)row * N + bn + tx * 4) = o;
        } else {
            float4 o = make_float4(v[0], v[1], v[2], v[3]);
            *(float4*)(Cf + (size_t)row * N + bn + tx * 4) = o;
        }
    }
}

// ---------------------------------------------------------------------------
extern "C" void kernel_launch(void* const* d_in, const int* in_sizes, int n_in,
                              void* d_out, int out_size, void* d_ws, size_t ws_size,
                              hipStream_t stream)
{
    const float* cond = (const float*)d_in[0];
    const int*   sig  = (const int*)d_in[1];
    const int*   tcrs = (const int*)d_in[2];
    const float* Wc   = (const float*)d_in[3];
    const float* Wf   = (const float*)d_in[4];
    const float* Whh  = (const float*)d_in[5];
    const float* bih  = (const float*)d_in[6];
    const float* bhh  = (const float*)d_in[7];
    const float* W1c  = (const float*)d_in[8];
    const float* b1c  = (const float*)d_in[9];
    const float* W2c  = (const float*)d_in[10];
    const float* b2c  = (const float*)d_in[11];
    const float* W1f  = (const float*)d_in[12];
    const float* b1f  = (const float*)d_in[13];
    const float* W2f  = (const float*)d_in[14];
    const float* b2f  = (const float*)d_in[15];

    char* ws = (char*)d_ws;
    int* slots               = (int*)ws;                         // 7,168 B (8K pad)
    unsigned long long* hx   = (unsigned long long*)(ws + 8192); // 57,344 B
    unsigned short* hc       = (unsigned short*)(ws + 65536);    // 29,360,128 B
    unsigned short* hid1     = (unsigned short*)(ws + 65536 + 29360128);

    float* outc  = (float*)d_out;
    float* outf  = outc + (size_t)BB * TT * NBINS;
    float* lasth = outc + 2 * (size_t)BB * TT * NBINS;

    void* args[] = {(void*)&cond, (void*)&sig, (void*)&tcrs, (void*)&Wc, (void*)&Wf,
                    (void*)&Whh, (void*)&bih, (void*)&bhh,
                    (void*)&hx, (void*)&slots, (void*)&hc, (void*)&lasth};
    hipLaunchCooperativeKernel((void*)scan_kernel, dim3(NWG), dim3(NTHR),
                               args, 0, stream);

    dim3 blk(256);
    head_gemm<1><<<dim3(512, 7), blk, 0, stream>>>(hc,   W1c, b1c, hid1, nullptr, 448);
    head_gemm<0><<<dim3(512, 4), blk, 0, stream>>>(hid1, W2c, b2c, nullptr, outc, 256);
    head_gemm<1><<<dim3(512, 7), blk, 0, stream>>>(hc,   W1f, b1f, hid1, nullptr, 448);
    head_gemm<0><<<dim3(512, 4), blk, 0, stream>>>(hid1, W2f, b2f, nullptr, outf, 256);
}

// Round 10
// 8092.568 us; speedup vs baseline: 1.1429x; 1.0105x over previous
//
#include <hip/hip_runtime.h>
#include <hip/hip_cooperative_groups.h>

namespace cg = cooperative_groups;

#define BB 16
#define TT 2048
#define HIDN 896
#define HALFN 448
#define NBINS 256
#define NWG 112
#define NTHR 64
#define WSTR 904            /* sW padded ushort stride */

typedef __attribute__((ext_vector_type(8))) short short8;
typedef __attribute__((ext_vector_type(4))) float f32x4;
typedef __attribute__((ext_vector_type(2))) unsigned long long ull2;

__device__ __forceinline__ unsigned short f2bf(float x) {
    unsigned int u = __float_as_uint(x);
    unsigned int r = u + 0x7FFFu + ((u >> 16) & 1u);
    return (unsigned short)(r >> 16);
}

// ---------------------------------------------------------------------------
// Persistent GRU scan. 112 WGs x 1 wave (64 thr). WG wg owns col-block
// cb = (wg&7)*14 + (wg>>3) (XCD remap), i.e. h-cols [8cb, 8cb+8).
// r9 structure (single WAITALL, fragment-direct hx loads, no LDS staging)
// plus REGISTER x-prefetch: cond/sig for step t+1 are loaded right AFTER
// step t's publish (behind the vmcnt(0) asm barrier), so step t+1's
// critical path has no fresh HBM dependency and WAITALL's poll drains
// only completed ops. Single register set (consumed by gates before the
// next prefetch overwrites). LDS exactly 57,856 B (proven coop envelope).
// ---------------------------------------------------------------------------
__global__ __launch_bounds__(NTHR, 1)
void scan_kernel(const float* __restrict__ cond,
                 const int*   __restrict__ sig,
                 const int*   __restrict__ tcrs,
                 const float* __restrict__ Wc,
                 const float* __restrict__ Wf,
                 const float* __restrict__ Whh,
                 const float* __restrict__ b_ih,
                 const float* __restrict__ b_hh,
                 unsigned long long* __restrict__ hx,   // [2][112][32] u64 (by cb)
                 int* __restrict__ slots,               // [112*16] padded
                 unsigned short* __restrict__ hc_out,
                 float* __restrict__ lasth)
{
    __shared__ unsigned short sW[32 * WSTR];   // 57,856 B (only LDS)

    const int tid  = threadIdx.x;
    const int wg   = blockIdx.x;
    const int cb   = (wg & 7) * 14 + (wg >> 3);   // XCD-contiguous col-block
    const int col0 = cb * 8;

    // ---- one-time: W slices -> LDS bf16 ----
    for (int idx = tid; idx < 32 * HIDN; idx += NTHR) {
        int j2 = idx & 31, k = idx >> 5;
        unsigned short wv = 0;
        if (j2 < 16)
            wv = f2bf(Whh[(size_t)k * 2688 + (j2 >> 3) * HIDN + col0 + (j2 & 7)]);
        else if (j2 < 24)
            wv = f2bf(Whh[(size_t)k * 2688 + 2 * HIDN + col0 + (j2 & 7)]);
        sW[j2 * WSTR + k] = wv;
    }
    if (tid == 0)
        __hip_atomic_store(&slots[wg * 16], 0, __ATOMIC_RELAXED, __HIP_MEMORY_SCOPE_AGENT);

    // ---- lane roles ----
    const int l  = tid;
    const int q  = l & 15;
    const int hi = l >> 4;
    const int gA   = q >> 3;            // 0 = r-gate, 1 = z-gate (tile A)
    const int colA = col0 + (q & 7);

    float wpA0, wpA1, wpA2, wpB0, wpB1, wpB2;
    if (colA < HALFN) {
        wpA0 = Wc[gA * HALFN + colA];
        wpA1 = Wc[1344 + gA * HALFN + colA];
        wpA2 = 0.f;
        wpB0 = Wc[2 * HALFN + colA];
        wpB1 = Wc[1344 + 2 * HALFN + colA];
        wpB2 = 0.f;
    } else {
        int ck = colA - HALFN;
        wpA0 = Wf[gA * HALFN + ck];
        wpA1 = Wf[1344 + gA * HALFN + ck];
        wpA2 = Wf[2688 + gA * HALFN + ck];
        wpB0 = Wf[2 * HALFN + ck];
        wpB1 = Wf[1344 + 2 * HALFN + ck];
        wpB2 = Wf[2688 + 2 * HALFN + ck];
    }
    const float biA = b_ih[gA * HIDN + colA];
    const float bhA = b_hh[gA * HIDN + colA];
    const float biB = b_ih[2 * HIDN + colA];
    const float bhB = b_hh[2 * HIDN + colA];

    float hp[4] = {0.f, 0.f, 0.f, 0.f};

    // ---- x prefetch registers (single set; overwritten post-publish) ----
    float xcA[4], xcB[4];
    int   si0[4], si1[4], si2[4];

#define PREFETCH(tt) {                                                         \
    int tn_ = (tt) < TT ? (tt) : TT - 1;                                       \
    _Pragma("unroll")                                                          \
    for (int r_ = 0; r_ < 4; ++r_) {                                           \
        size_t bt_ = (size_t)(hi * 4 + r_) * TT + tn_;                         \
        xcA[r_] = cond[(bt_ * 3 + gA) * HIDN + colA];                          \
        xcB[r_] = cond[(bt_ * 3 + 2) * HIDN + colA];                           \
        si0[r_] = sig[bt_ * 2 + 0];                                            \
        si1[r_] = sig[bt_ * 2 + 1];                                            \
        si2[r_] = tcrs[bt_];                                                   \
    } }

    PREFETCH(0);                      // x for t=0 (completes during prologue)

    __syncthreads();                 // sW visible wave-wide
    cg::this_grid().sync();          // slot clears visible grid-wide

    const float inv = 1.f / 127.5f;
    const int zsrc = (l & 48) | 8 | (q & 7);   // z-lane, same hi

    // ---- single wait on all 112 producer slots ----
#define WAITALL(t) { bool ok_;                                                 \
    for (;;) {                                                                 \
        int a_ = __hip_atomic_load(&slots[l * 16],                             \
            __ATOMIC_RELAXED, __HIP_MEMORY_SCOPE_AGENT);                       \
        int b_ = (l < 48) ? __hip_atomic_load(&slots[(l + 64) * 16],           \
            __ATOMIC_RELAXED, __HIP_MEMORY_SCOPE_AGENT) : a_;                  \
        ok_ = (a_ >= (t)) & (b_ >= (t));                                       \
        if (__all(ok_)) break;                                                 \
        __builtin_amdgcn_s_sleep(1);                                           \
    }                                                                          \
    asm volatile("" ::: "memory"); }

    // Lane (q,hi): A-frag for K-step ks = cols of col-block 4ks+hi, batch q.
#define LOADH(s, V) _Pragma("unroll")                                          \
    for (int i_ = 0; i_ < 7; ++i_) {                                           \
        _Pragma("unroll")                                                      \
        for (int h_ = 0; h_ < 2; ++h_)                                         \
            V[2*i_ + h_] = __hip_atomic_load(                                  \
                &hb[(size_t)(4 * ((s)*7 + i_) + hi) * 32 + h_ * 16 + q],       \
                __ATOMIC_RELAXED, __HIP_MEMORY_SCOPE_AGENT);                   \
    }

#define MFMAS(s, V) _Pragma("unroll")                                          \
    for (int i_ = 0; i_ < 7; ++i_) {                                           \
        ull2 tv_; tv_.x = V[2*i_]; tv_.y = V[2*i_ + 1];                        \
        short8 av_ = __builtin_bit_cast(short8, tv_);                          \
        int ks_ = (s)*7 + i_;                                                  \
        short8 b1_ = *(const short8*)&sW[q * WSTR + hi * 8 + ks_ * 32];        \
        chA[ks_ & 3] = __builtin_amdgcn_mfma_f32_16x16x32_bf16(                \
            av_, b1_, chA[ks_ & 3], 0, 0, 0);                                  \
        short8 b2_ = *(const short8*)&sW[(16 + q) * WSTR + hi * 8 + ks_ * 32]; \
        chB[ks_ & 3] = __builtin_amdgcn_mfma_f32_16x16x32_bf16(                \
            av_, b2_, chB[ks_ & 3], 0, 0, 0);                                  \
    }

    for (int t = 0; t < TT; ++t) {
        f32x4 chA[4] = {}, chB[4] = {};
        if (t > 0) {
            WAITALL(t);
            const unsigned long long* hb = hx + (size_t)(t & 1) * 3584;
            unsigned long long va[14], vb[14];
            LOADH(0, va);
            LOADH(1, vb);
            MFMAS(0, va);
            LOADH(2, va);
            MFMAS(1, vb);
            LOADH(3, vb);
            MFMAS(2, va);
            MFMAS(3, vb);
        }
        f32x4 aA = (chA[0] + chA[1]) + (chA[2] + chA[3]);
        f32x4 aB = (chB[0] + chB[1]) + (chB[2] + chB[3]);

        // ---- gates (x from prefetched regs -- no fresh HBM deps) ----
        float xvB[4], sigA[4];
        #pragma unroll
        for (int r = 0; r < 4; ++r) {
            float g0 = (float)si0[r] * inv - 1.f;
            float g1 = (float)si1[r] * inv - 1.f;
            float g2 = (float)si2[r] * inv - 1.f;
            float xvA = xcA[r] + biA + g0*wpA0 + g1*wpA1 + g2*wpA2;
            xvB[r]    = xcB[r] + biB + g0*wpB0 + g1*wpB1 + g2*wpB2;
            sigA[r] = 1.f / (1.f + __expf(-(xvA + aA[r] + bhA)));
        }
        float hnv[4];
        unsigned short hbits[4] = {0, 0, 0, 0};
        #pragma unroll
        for (int r = 0; r < 4; ++r) {
            float zz = __shfl(sigA[r], zsrc);          // z from q+8 lane
            float a2v = xvB[r] + sigA[r] * (aB[r] + bhB);  // r on q<8 lanes
            float e = __expf(-2.f * a2v);
            float n = (1.f - e) / (1.f + e);
            float hn = (1.f - zz) * n + zz * hp[r];
            hnv[r] = hn;
            if (q < 8) { hp[r] = hn; hbits[r] = f2bf(hn); }
        }
        if (t == TT - 1 && q < 8) {
            #pragma unroll
            for (int r = 0; r < 4; ++r)
                lasth[(size_t)(hi * 4 + r) * HIDN + colA] = hnv[r];
        }

        // ---- pack 8 cols -> 2 u64 per batch; store; drain; publish ----
        unsigned p32[4];
        unsigned long long hv64[4];
        #pragma unroll
        for (int r = 0; r < 4; ++r) {
            int o1 = __shfl_xor((int)(unsigned)hbits[r], 1);
            p32[r] = ((unsigned)hbits[r] & 0xffffu) | ((unsigned)o1 << 16);
            int o2 = __shfl_xor((int)p32[r], 2);
            hv64[r] = (unsigned long long)p32[r] |
                      ((unsigned long long)(unsigned)o2 << 32);
        }
        if (t < TT - 1 && (q == 0 || q == 4)) {
            unsigned long long* hd = hx + (size_t)((t + 1) & 1) * 3584;
            #pragma unroll
            for (int r = 0; r < 4; ++r)
                __hip_atomic_store(&hd[(size_t)cb * 32 + (q >> 2) * 16 + hi * 4 + r],
                                   hv64[r], __ATOMIC_RELAXED, __HIP_MEMORY_SCOPE_AGENT);
        }
        asm volatile("s_waitcnt vmcnt(0)" ::: "memory");
        if (tid == 0)
            __hip_atomic_store(&slots[wg * 16], t + 1,
                               __ATOMIC_RELAXED, __HIP_MEMORY_SCOPE_AGENT);

        // ---- post-publish: prefetch next x (full step of latency slack),
        //      then history write -- both off the critical path ----
        PREFETCH(t + 1);
        if (cb < 56 && q < 8 && !(q & 1)) {
            unsigned* hc32 = (unsigned*)hc_out;
            #pragma unroll
            for (int r = 0; r < 4; ++r)
                hc32[((size_t)(hi * 4 + r) * TT + t) * 224 + cb * 4 + (q >> 1)] = p32[r];
        }
    }
#undef WAITALL
#undef LOADH
#undef MFMAS
#undef PREFETCH
}

// ---------------------------------------------------------------------------
// Head GEMM: C(M x N) = [relu](A_bf16(M x 448) @ Bw(448 x N) + bias)
// ---------------------------------------------------------------------------
template<int RELU_BF16>
__global__ __launch_bounds__(256)
void head_gemm(const unsigned short* __restrict__ A,
               const float* __restrict__ Bw,
               const float* __restrict__ bias,
               unsigned short* __restrict__ Cb,
               float* __restrict__ Cf,
               int N)
{
    const int K = 448;
    __shared__ float As[32][68];
    __shared__ float Bs[32][68];
    const int tid = threadIdx.x;
    const int tx = tid & 15;
    const int ty = tid >> 4;
    const int bm = blockIdx.x * 64;
    const int bn = blockIdx.y * 64;

    float acc[4][4] = {};

    for (int k0 = 0; k0 < K; k0 += 32) {
        #pragma unroll
        for (int it = 0; it < 2; ++it) {
            int idx = tid + it * 256;
            int m   = idx >> 3;
            int k4  = idx & 7;
            ushort4 av = *(const ushort4*)(A + (size_t)(bm + m) * K + k0 + k4 * 4);
            As[k4 * 4 + 0][m] = __uint_as_float((unsigned)av.x << 16);
            As[k4 * 4 + 1][m] = __uint_as_float((unsigned)av.y << 16);
            As[k4 * 4 + 2][m] = __uint_as_float((unsigned)av.z << 16);
            As[k4 * 4 + 3][m] = __uint_as_float((unsigned)av.w << 16);
        }
        #pragma unroll
        for (int it = 0; it < 2; ++it) {
            int idx = tid + it * 256;
            int k   = idx >> 4;
            int n4  = idx & 15;
            *(float4*)&Bs[k][n4 * 4] =
                *(const float4*)(Bw + (size_t)(k0 + k) * N + bn + n4 * 4);
        }
        __syncthreads();
        #pragma unroll
        for (int k = 0; k < 32; ++k) {
            float4 a4 = *(float4*)&As[k][ty * 4];
            float4 b4 = *(float4*)&Bs[k][tx * 4];
            float ar[4] = {a4.x, a4.y, a4.z, a4.w};
            float br[4] = {b4.x, b4.y, b4.z, b4.w};
            #pragma unroll
            for (int i = 0; i < 4; ++i)
                #pragma unroll
                for (int j = 0; j < 4; ++j)
                    acc[i][j] = fmaf(ar[i], br[j], acc[i][j]);
        }
        __syncthreads();
    }

    float4 bsv = *(const float4*)(bias + bn + tx * 4);
    float bb[4] = {bsv.x, bsv.y, bsv.z, bsv.w};
    #pragma unroll
    for (int i = 0; i < 4; ++i) {
        int row = bm + ty * 4 + i;
        float v[4];
        #pragma unroll
        for (int j = 0; j < 4; ++j) v[j] = acc[i][j] + bb[j];
        if (RELU_BF16) {
            ushort4 o;
            o.x = f2bf(fmaxf(v[0], 0.f));
            o.y = f2bf(fmaxf(v[1], 0.f));
            o.z = f2bf(fmaxf(v[2], 0.f));
            o.w = f2bf(fmaxf(v[3], 0.f));
            *(ushort4*)(Cb + (size_t)row * N + bn + tx * 4) = o;
        } else {
            float4 o = make_float4(v[0], v[1], v[2], v[3]);
            *(float4*)(Cf + (size_t)row * N + bn + tx * 4) = o;
        }
    }
}

// ---------------------------------------------------------------------------
extern "C" void kernel_launch(void* const* d_in, const int* in_sizes, int n_in,
                              void* d_out, int out_size, void* d_ws, size_t ws_size,
                              hipStream_t stream)
{
    const float* cond = (const float*)d_in[0];
    const int*   sig  = (const int*)d_in[1];
    const int*   tcrs = (const int*)d_in[2];
    const float* Wc   = (const float*)d_in[3];
    const float* Wf   = (const float*)d_in[4];
    const float* Whh  = (const float*)d_in[5];
    const float* bih  = (const float*)d_in[6];
    const float* bhh  = (const float*)d_in[7];
    const float* W1c  = (const float*)d_in[8];
    const float* b1c  = (const float*)d_in[9];
    const float* W2c  = (const float*)d_in[10];
    const float* b2c  = (const float*)d_in[11];
    const float* W1f  = (const float*)d_in[12];
    const float* b1f  = (const float*)d_in[13];
    const float* W2f  = (const float*)d_in[14];
    const float* b2f  = (const float*)d_in[15];

    char* ws = (char*)d_ws;
    int* slots               = (int*)ws;                         // 7,168 B (8K pad)
    unsigned long long* hx   = (unsigned long long*)(ws + 8192); // 57,344 B
    unsigned short* hc       = (unsigned short*)(ws + 65536);    // 29,360,128 B
    unsigned short* hid1     = (unsigned short*)(ws + 65536 + 29360128);

    float* outc  = (float*)d_out;
    float* outf  = outc + (size_t)BB * TT * NBINS;
    float* lasth = outc + 2 * (size_t)BB * TT * NBINS;

    void* args[] = {(void*)&cond, (void*)&sig, (void*)&tcrs, (void*)&Wc, (void*)&Wf,
                    (void*)&Whh, (void*)&bih, (void*)&bhh,
                    (void*)&hx, (void*)&slots, (void*)&hc, (void*)&lasth};
    hipLaunchCooperativeKernel((void*)scan_kernel, dim3(NWG), dim3(NTHR),
                               args, 0, stream);

    dim3 blk(256);
    head_gemm<1><<<dim3(512, 7), blk, 0, stream>>>(hc,   W1c, b1c, hid1, nullptr, 448);
    head_gemm<0><<<dim3(512, 4), blk, 0, stream>>>(hid1, W2c, b2c, nullptr, outc, 256);
    head_gemm<1><<<dim3(512, 7), blk, 0, stream>>>(hc,   W1f, b1f, hid1, nullptr, 448);
    head_gemm<0><<<dim3(512, 4), blk, 0, stream>>>(hid1, W2f, b2f, nullptr, outf, 256);
}